// Round 17
// baseline (212.799 us; speedup 1.0000x reference)
//
#include <hip/hip_runtime.h>

typedef unsigned short ushort_t;
typedef unsigned int uint_t;

typedef short bf16x8 __attribute__((ext_vector_type(8)));
typedef float f32x4 __attribute__((ext_vector_type(4)));
#define MFMA16(a, b, c) __builtin_amdgcn_mfma_f32_16x16x32_bf16(a, b, c, 0, 0, 0)

__device__ __forceinline__ float bf2f(uint_t u) { return __uint_as_float(u << 16); }
__device__ __forceinline__ ushort_t f2bf(float f) {
  uint_t x = __float_as_uint(f);
  return (ushort_t)((x + 0x7fffu + ((x >> 16) & 1u)) >> 16);  // RNE
}
__device__ __forceinline__ uint_t cvtpk(float lo, float hi) {
  uint_t r;
  asm("v_cvt_pk_bf16_f32 %0, %1, %2" : "=v"(r) : "v"(lo), "v"(hi));
  return r;
}
// async global->LDS, 16B per lane; LDS dest is wave-uniform base + lane*16
__device__ __forceinline__ void gload_lds16(const void* g, void* l) {
  __builtin_amdgcn_global_load_lds(
      (const __attribute__((address_space(1))) unsigned int*)g,
      (__attribute__((address_space(3))) unsigned int*)l, 16, 0, 0);
}

// B=64,R=32 -> N=2048; L=64; C0=128, C1=C2=256, C3=16. f32 inputs/output.
#define NBATCH 2048

// ---------- pre0: per-n channel means of H + V2_0[n][o]; blocks<128 also cvt W0 ----------
__global__ __launch_bounds__(256) void pre0_kernel(
    const float* __restrict__ Hr, const float* __restrict__ Hi,
    const float* __restrict__ P2_0, const float* __restrict__ P1_0,
    ushort_t* __restrict__ W0bf, float* __restrict__ V20)
{
  __shared__ float r[4][128];
  __shared__ float hm[128];
  const int t = threadIdx.x, n = blockIdx.x;
  if (n < 128) {
    int i = n * 256 + t;
    W0bf[i] = f2bf(P1_0[i]);
  }
  const int q = t >> 6;
  const int c = (2 * t) & 127;
  const int cc = c & 63;
  const float* src = ((c < 64) ? Hr : Hi) + (size_t)n * 4096 + cc;
  float s0 = 0.f, s1 = 0.f;
  #pragma unroll
  for (int i = 0; i < 16; i++) {
    int l = 4 * i + q;
    float2 x = *(const float2*)(src + l * 64);
    s0 += x.x; s1 += x.y;
  }
  r[q][c] = s0; r[q][c + 1] = s1;
  __syncthreads();
  if (t < 128) hm[t] = (r[0][t] + r[1][t] + r[2][t] + r[3][t]) * (1.0f / 64.0f);
  __syncthreads();
  const float4* pw = (const float4*)(P2_0 + t * 128);
  float s = 0.f;
  #pragma unroll 8
  for (int c4 = 0; c4 < 32; c4++) {
    float4 p = pw[c4];
    s = fmaf(p.x, hm[4 * c4 + 0], s);
    s = fmaf(p.y, hm[4 * c4 + 1], s);
    s = fmaf(p.z, hm[4 * c4 + 2], s);
    s = fmaf(p.w, hm[4 * c4 + 3], s);
  }
  V20[n * 256 + t] = 0.1f * s;
}

// ---------- layer0: dbuf 2-batch async-staged (f32, swizzled) MFMA GEMM(128->256) ----------
__global__ __launch_bounds__(256) void layer0_mfma_kernel(
    const float* __restrict__ Hr, const float* __restrict__ Hi,
    const ushort_t* __restrict__ W0bf, const float* __restrict__ V20,
    ushort_t* __restrict__ Z, float* __restrict__ partA, float* __restrict__ partB)
{
  __shared__ __align__(16) ushort_t lds[2][64 * 264];  // 2 x 33.8 KB regions
  const int t = threadIdx.x, nb = blockIdx.x;
  const int lane = t & 63, w = t >> 6, r16 = lane & 15, g4 = lane >> 4;
  const int sw = r16 & 7;

  // stage H[n] (f32, source-swizzled): granule G: row=G>>5, gc=G&31; src granule gc^(row&7)
  auto stageH = [&](float* bufF, int n) {
    #pragma unroll
    for (int i = 0; i < 8; i++) {
      int G = (w * 8 + i) * 64 + lane;
      int row = G >> 5;
      int gc = G & 31;
      int gsrc = gc ^ (row & 7);
      int fi = gsrc * 4;   // f32 col in [0,128): <64 Hr else Hi
      const float* src = ((fi < 64) ? Hr : Hi) + (size_t)n * 4096 + row * 64 + (fi & 63);
      gload_lds16(src, bufF + (w * 8 + i) * 256);
    }
  };

  stageH((float*)&lds[0][0], 2 * nb);
  __syncthreads();                         // buf0 staged
  stageH((float*)&lds[1][0], 2 * nb + 1);  // async; overlaps half-0 compute

  #pragma unroll
  for (int half = 0; half < 2; half++) {
    const int n = 2 * nb + half;
    ushort_t* buf = &lds[half][0];
    float* bufF = (float*)buf;

    float4 v2r[4];
    #pragma unroll
    for (int m = 0; m < 4; m++)
      v2r[m] = *(const float4*)(V20 + n * 256 + w * 64 + m * 16 + g4 * 4);

    f32x4 acc[4][4];
    #pragma unroll
    for (int i = 0; i < 4; i++)
      #pragma unroll
      for (int j = 0; j < 4; j++) acc[i][j] = (f32x4){0.f, 0.f, 0.f, 0.f};

    #pragma unroll
    for (int kk = 0; kk < 4; kk++) {
      bf16x8 aF[4], bF[4];
      #pragma unroll
      for (int m = 0; m < 4; m++)
        aF[m] = *(const bf16x8*)(W0bf + (w * 64 + m * 16 + r16) * 128 + kk * 32 + g4 * 8);
      #pragma unroll
      for (int nt = 0; nt < 4; nt++) {
        const int row = nt * 16 + r16;
        const float* base = bufF + row * 128;
        const int g0 = kk * 8 + g4 * 2;
        float4 xa = *(const float4*)(base + ((g0 ^ sw) * 4));
        float4 xb = *(const float4*)(base + (((g0 + 1) ^ sw) * 4));
        uint4 u = make_uint4(cvtpk(xa.x, xa.y), cvtpk(xa.z, xa.w),
                             cvtpk(xb.x, xb.y), cvtpk(xb.z, xb.w));
        bF[nt] = *(const bf16x8*)&u;
      }
      #pragma unroll
      for (int m = 0; m < 4; m++)
        #pragma unroll
        for (int nt = 0; nt < 4; nt++)
          acc[m][nt] = MFMA16(aF[m], bF[nt], acc[m][nt]);
    }

    // fused stats
    #pragma unroll
    for (int m = 0; m < 4; m++) {
      float s[4] = {0.f, 0.f, 0.f, 0.f}, q[4] = {0.f, 0.f, 0.f, 0.f};
      #pragma unroll
      for (int nt = 0; nt < 4; nt++)
        #pragma unroll
        for (int r = 0; r < 4; r++) {
          float v = fmaxf(acc[m][nt][r] + v2r[m][r], 0.f);
          s[r] += v; q[r] = fmaf(v, v, q[r]);
        }
      #pragma unroll
      for (int b = 1; b < 16; b <<= 1)
        #pragma unroll
        for (int r = 0; r < 4; r++) {
          s[r] += __shfl_xor(s[r], b);
          q[r] += __shfl_xor(q[r], b);
        }
      const int ob = w * 64 + m * 16 + g4 * 4;
      #pragma unroll
      for (int r = 0; r < 4; r++)
        if (r16 == r) {
          partA[n * 256 + ob + r] = s[r];
          partB[n * 256 + ob + r] = q[r];
        }
    }

    __syncthreads();   // buf reads done (half 0: also drains buf1 stage)
    #pragma unroll
    for (int m = 0; m < 4; m++) {
      const int ob = w * 64 + m * 16 + g4 * 4;
      #pragma unroll
      for (int nt = 0; nt < 4; nt++) {
        const int l = nt * 16 + r16;
        uint_t p0 = cvtpk(fmaxf(acc[m][nt][0] + v2r[m].x, 0.f),
                          fmaxf(acc[m][nt][1] + v2r[m].y, 0.f));
        uint_t p1 = cvtpk(fmaxf(acc[m][nt][2] + v2r[m].z, 0.f),
                          fmaxf(acc[m][nt][3] + v2r[m].w, 0.f));
        *(uint2*)(&buf[l * 264 + ob]) = make_uint2(p0, p1);
      }
    }
    __syncthreads();
    #pragma unroll
    for (int i = 0; i < 8; i++) {
      int el = i * 2048 + t * 8;
      int l = el >> 8, o0 = el & 255;
      *(uint4*)(&Z[(size_t)n * 16384 + el]) = *(const uint4*)(&buf[l * 264 + o0]);
    }
  }
}

// ---------- statsfin ----------
__global__ __launch_bounds__(256) void statsfin_kernel(
    const float* __restrict__ partA, const float* __restrict__ partB,
    const float* __restrict__ bnw, const float* __restrict__ bnb,
    float* __restrict__ stats)
{
  __shared__ float s1s[256], s2s[256];
  const int c = blockIdx.x, t = threadIdx.x;
  float s1 = 0.f, s2 = 0.f;
  #pragma unroll
  for (int j = 0; j < 8; j++) {
    int n = t * 8 + j;
    s1 += partA[n * 256 + c];
    s2 += partB[n * 256 + c];
  }
  s1s[t] = s1; s2s[t] = s2;
  __syncthreads();
  for (int s = 128; s > 0; s >>= 1) {
    if (t < s) { s1s[t] += s1s[t + s]; s2s[t] += s2s[t + s]; }
    __syncthreads();
  }
  if (t == 0) {
    const float inv = 1.0f / 131072.0f;
    float mu = s1s[0] * inv;
    float var = fmaxf(s2s[0] * inv - mu * mu, 0.f);
    float rstd = rsqrtf(var + 1e-5f);
    float sc = rstd * bnw[c];
    stats[2 * c]     = sc;
    stats[2 * c + 1] = bnb[c] - mu * sc;
  }
}

// ---------- prep ----------
__global__ __launch_bounds__(256) void prep_kernel(
    const float* __restrict__ P1f, const float* __restrict__ P2f,
    const float* __restrict__ stats, ushort_t* __restrict__ Wbf,
    float* __restrict__ P2s, float* __restrict__ biasT)
{
  const int o = blockIdx.x, t = threadIdx.x;
  float sc = stats[2 * t], sh = stats[2 * t + 1];
  float w = P1f[o * 256 + t];
  Wbf[o * 256 + t] = f2bf(w * sc);
  float p = P2f[o * 256 + t];
  P2s[o * 256 + t] = p * sc;
  __shared__ float s1[256], s2[256];
  s1[t] = w * sh;
  s2[t] = p * sh;
  __syncthreads();
  for (int s = 128; s > 0; s >>= 1) {
    if (t < s) { s1[t] += s1[t + s]; s2[t] += s2[t + s]; }
    __syncthreads();
  }
  if (t == 0) biasT[o] = s1[0] + 0.1f * s2[0];
}

// ---------- layer1: dbuf 2-batch async-staged GEMM(256->256) + fused v2 (v2n) + stats; in-place Z ----------
__global__ __launch_bounds__(256) void layer1_mfma_kernel(
    ushort_t* Z, const ushort_t* __restrict__ W1bf,
    const float* __restrict__ P2s1, const float* __restrict__ biasT,
    float* __restrict__ partA, float* __restrict__ partB)
{
  __shared__ __align__(16) ushort_t lds[2][64 * 264];
  __shared__ float zmS[2][256];
  __shared__ float v2sS[2][256];
  const int t = threadIdx.x, nb = blockIdx.x;
  const int lane = t & 63, w = t >> 6, r16 = lane & 15, g4 = lane >> 4;
  const int sw = r16 & 7;
  const int n0 = 2 * nb, n1 = 2 * nb + 1;

  auto stageZ = [&](ushort_t* buf, int n) {
    const size_t zb = (size_t)n * 16384;
    #pragma unroll
    for (int i = 0; i < 8; i++) {
      int G = (w * 8 + i) * 64 + lane;
      int row = G >> 5;
      int gc = G & 31;
      int gsrc = gc ^ (row & 7);
      gload_lds16(Z + zb + row * 256 + gsrc * 8, buf + (w * 8 + i) * 512);
    }
  };

  stageZ(&lds[0][0], n0);
  zmS[0][t] = partA[n0 * 256 + t] * (1.0f / 64.0f);   // layer0's partA = per-n sums
  zmS[1][t] = partA[n1 * 256 + t] * (1.0f / 64.0f);
  __syncthreads();                  // stage0 done + zm visible
  stageZ(&lds[1][0], n1);           // async; overlaps v2 dot

  // fused v2n: v2[h][o=t] = 0.1 * P2s1[o,:].zm[h] + biasT[o]
  {
    const float4* pw = (const float4*)(P2s1 + t * 256);
    float s0 = 0.f, s1 = 0.f;
    #pragma unroll 4
    for (int c4 = 0; c4 < 64; c4++) {
      float4 p = pw[c4];
      s0 = fmaf(p.x, zmS[0][4 * c4 + 0], s0);
      s0 = fmaf(p.y, zmS[0][4 * c4 + 1], s0);
      s0 = fmaf(p.z, zmS[0][4 * c4 + 2], s0);
      s0 = fmaf(p.w, zmS[0][4 * c4 + 3], s0);
      s1 = fmaf(p.x, zmS[1][4 * c4 + 0], s1);
      s1 = fmaf(p.y, zmS[1][4 * c4 + 1], s1);
      s1 = fmaf(p.z, zmS[1][4 * c4 + 2], s1);
      s1 = fmaf(p.w, zmS[1][4 * c4 + 3], s1);
    }
    float b = biasT[t];
    v2sS[0][t] = 0.1f * s0 + b;
    v2sS[1][t] = 0.1f * s1 + b;
  }
  __syncthreads();                  // v2s visible (also drains stage1)

  #pragma unroll
  for (int half = 0; half < 2; half++) {
    const int n = 2 * nb + half;
    ushort_t* buf = &lds[half][0];
    const size_t zbase = (size_t)n * 16384;

    float4 v2r[4];
    #pragma unroll
    for (int m = 0; m < 4; m++)
      v2r[m] = *(const float4*)(&v2sS[half][w * 64 + m * 16 + g4 * 4]);

    f32x4 acc[4][4];
    #pragma unroll
    for (int i = 0; i < 4; i++)
      #pragma unroll
      for (int j = 0; j < 4; j++) acc[i][j] = (f32x4){0.f, 0.f, 0.f, 0.f};

    bf16x8 aF[2][4];
    #pragma unroll
    for (int m = 0; m < 4; m++)
      aF[0][m] = *(const bf16x8*)(W1bf + (w * 64 + m * 16 + r16) * 256 + g4 * 8);

    #pragma unroll
    for (int kk = 0; kk < 8; kk++) {
      const int cur = kk & 1, nxt = cur ^ 1;
      if (kk < 7) {
        #pragma unroll
        for (int m = 0; m < 4; m++)
          aF[nxt][m] = *(const bf16x8*)(W1bf + (w * 64 + m * 16 + r16) * 256 + (kk + 1) * 32 + g4 * 8);
      }
      bf16x8 bF[4];
      #pragma unroll
      for (int nt = 0; nt < 4; nt++) {
        const int row = nt * 16 + r16;
        bF[nt] = *(const bf16x8*)(&buf[row * 256 + (((kk * 4 + g4) ^ sw) * 8)]);
      }
      #pragma unroll
      for (int m = 0; m < 4; m++)
        #pragma unroll
        for (int nt = 0; nt < 4; nt++)
          acc[m][nt] = MFMA16(aF[cur][m], bF[nt], acc[m][nt]);
    }

    #pragma unroll
    for (int m = 0; m < 4; m++) {
      float s[4] = {0.f, 0.f, 0.f, 0.f}, q[4] = {0.f, 0.f, 0.f, 0.f};
      #pragma unroll
      for (int nt = 0; nt < 4; nt++)
        #pragma unroll
        for (int r = 0; r < 4; r++) {
          float v = fmaxf(acc[m][nt][r] + v2r[m][r], 0.f);
          s[r] += v; q[r] = fmaf(v, v, q[r]);
        }
      #pragma unroll
      for (int b = 1; b < 16; b <<= 1)
        #pragma unroll
        for (int r = 0; r < 4; r++) {
          s[r] += __shfl_xor(s[r], b);
          q[r] += __shfl_xor(q[r], b);
        }
      const int ob = w * 64 + m * 16 + g4 * 4;
      #pragma unroll
      for (int r = 0; r < 4; r++)
        if (r16 == r) {
          partA[n * 256 + ob + r] = s[r];
          partB[n * 256 + ob + r] = q[r];
        }
    }

    __syncthreads();   // buf reads done
    #pragma unroll
    for (int m = 0; m < 4; m++) {
      const int ob = w * 64 + m * 16 + g4 * 4;
      #pragma unroll
      for (int nt = 0; nt < 4; nt++) {
        const int l = nt * 16 + r16;
        uint_t p0 = cvtpk(fmaxf(acc[m][nt][0] + v2r[m].x, 0.f),
                          fmaxf(acc[m][nt][1] + v2r[m].y, 0.f));
        uint_t p1 = cvtpk(fmaxf(acc[m][nt][2] + v2r[m].z, 0.f),
                          fmaxf(acc[m][nt][3] + v2r[m].w, 0.f));
        *(uint2*)(&buf[l * 264 + ob]) = make_uint2(p0, p1);
      }
    }
    __syncthreads();
    #pragma unroll
    for (int i = 0; i < 8; i++) {
      int el = i * 2048 + t * 8;
      int l = el >> 8, o0 = el & 255;
      *(uint4*)(&Z[zbase + el]) = *(const uint4*)(&buf[l * 264 + o0]);
    }
  }
}

// ---------- layer2 + final + v2w fused ----------
__global__ __launch_bounds__(256) void layer2final_kernel(
    const ushort_t* __restrict__ Z, const ushort_t* __restrict__ W2bf,
    const float* __restrict__ partA, const float* __restrict__ P2s2,
    const float* __restrict__ biasT2, const float* __restrict__ Vh,
    float* __restrict__ out)
{
  __shared__ float zm[256];
  __shared__ float red[16][17];
  __shared__ float v2s[16];
  __shared__ float zf[16][65];
  __shared__ float invn[16];
  const int t = threadIdx.x, n = blockIdx.x;
  const int lane = t & 63, w = t >> 6, r16 = lane & 15, g4 = lane >> 4;
  const size_t zbase = (size_t)n * 16384;

  zm[t] = partA[n * 256 + t] * (1.0f / 64.0f);

  f32x4 acc = (f32x4){0.f, 0.f, 0.f, 0.f};
  #pragma unroll 2
  for (int kk = 0; kk < 8; kk++) {
    bf16x8 aF = *(const bf16x8*)(W2bf + r16 * 256 + kk * 32 + g4 * 8);
    bf16x8 bF = *(const bf16x8*)(Z + zbase + (w * 16 + r16) * 256 + kk * 32 + g4 * 8);
    acc = MFMA16(aF, bF, acc);
  }
  __syncthreads();   // zm visible
  {
    const int oi = t & 15, ch = t >> 4;
    const float4* pw = (const float4*)(P2s2 + oi * 256 + ch * 16);
    float s = 0.f;
    #pragma unroll
    for (int c4 = 0; c4 < 4; c4++) {
      float4 p = pw[c4];
      int cb = ch * 16 + c4 * 4;
      s = fmaf(p.x, zm[cb + 0], s);
      s = fmaf(p.y, zm[cb + 1], s);
      s = fmaf(p.z, zm[cb + 2], s);
      s = fmaf(p.w, zm[cb + 3], s);
    }
    red[ch][oi] = s;
  }
  __syncthreads();
  if (t < 16) {
    float a = 0.f;
    #pragma unroll
    for (int c = 0; c < 16; c++) a += red[c][t];
    v2s[t] = 0.1f * a + biasT2[t];
  }
  __syncthreads();
  #pragma unroll
  for (int r = 0; r < 4; r++) {
    int o = g4 * 4 + r;
    zf[o][w * 16 + r16] = acc[r] + v2s[o];
  }
  __syncthreads();
  if (t < 16) {
    float s = 0.f;
    #pragma unroll
    for (int l = 0; l < 64; l++) s = fmaf(zf[t][l], zf[t][l], s);
    invn[t] = (s > 0.f) ? (8.0f * rsqrtf(s)) : 0.f;
  }
  __syncthreads();
  const size_t base = (size_t)n * 4096;
  #pragma unroll
  for (int g = 0; g < 4; g++) {
    int e = t * 16 + g * 4;
    int l = e >> 6;
    int k = (e >> 2) & 15;
    float val = zf[k][l] * invn[k];
    float4 vv = *(const float4*)(Vh + base + e);
    *(float4*)(out + base + e) =
        make_float4(vv.x * val, vv.y * val, vv.z * val, vv.w * val);
  }
}

extern "C" void kernel_launch(void* const* d_in, const int* in_sizes, int n_in,
                              void* d_out, int out_size, void* d_ws, size_t ws_size,
                              hipStream_t stream) {
  const float* Hr   = (const float*)d_in[0];
  const float* Hi   = (const float*)d_in[1];
  const float* Vh   = (const float*)d_in[2];
  const float* P1_0 = (const float*)d_in[3];
  const float* P2_0 = (const float*)d_in[4];
  const float* bnw0 = (const float*)d_in[5];
  const float* bnb0 = (const float*)d_in[6];
  const float* P1_1 = (const float*)d_in[7];
  const float* P2_1 = (const float*)d_in[8];
  const float* bnw1 = (const float*)d_in[9];
  const float* bnb1 = (const float*)d_in[10];
  const float* P1_2 = (const float*)d_in[11];
  const float* P2_2 = (const float*)d_in[12];

  char* ws = (char*)d_ws;
  float*    stats0 = (float*)   (ws);             // 2048
  float*    stats1 = (float*)   (ws + 2048);      // 2048
  float*    biasT  = (float*)   (ws + 4096);      // 1024
  float*    biasT2 = (float*)   (ws + 5120);      // 1024
  ushort_t* W0bf   = (ushort_t*)(ws + 8192);      // 65536
  ushort_t* W1bf   = (ushort_t*)(ws + 73728);     // 131072
  ushort_t* W2bf   = (ushort_t*)(ws + 204800);    // 8192
  float*    P2s1   = (float*)   (ws + 212992);    // 262144
  float*    P2s2   = (float*)   (ws + 475136);    // 16384
  float*    partA  = (float*)   (ws + 491520);    // 2097152
  float*    partB  = (float*)   (ws + 2588672);   // 2097152
  float*    V20    = (float*)   (ws + 4685824);   // 2097152
  ushort_t* Z      = (ushort_t*)(ws + 9437184);   // 67108864 -> end 76,546,048

  pre0_kernel<<<NBATCH, 256, 0, stream>>>(Hr, Hi, P2_0, P1_0, W0bf, V20);
  layer0_mfma_kernel<<<NBATCH / 2, 256, 0, stream>>>(Hr, Hi, W0bf, V20, Z, partA, partB);
  statsfin_kernel<<<256, 256, 0, stream>>>(partA, partB, bnw0, bnb0, stats0);
  prep_kernel<<<256, 256, 0, stream>>>(P1_1, P2_1, stats0, W1bf, P2s1, biasT);
  layer1_mfma_kernel<<<NBATCH / 2, 256, 0, stream>>>(Z, W1bf, P2s1, biasT, partA, partB);
  statsfin_kernel<<<256, 256, 0, stream>>>(partA, partB, bnw1, bnb1, stats1);
  prep_kernel<<<16, 256, 0, stream>>>(P1_2, P2_2, stats1, W2bf, P2s2, biasT2);
  layer2final_kernel<<<NBATCH, 256, 0, stream>>>(Z, W2bf, partA, P2s2, biasT2, Vh, (float*)d_out);
}

// Round 18
// 200.370 us; speedup vs baseline: 1.0620x; 1.0620x over previous
//
#include <hip/hip_runtime.h>

typedef unsigned short ushort_t;
typedef unsigned int uint_t;

typedef short bf16x8 __attribute__((ext_vector_type(8)));
typedef float f32x4 __attribute__((ext_vector_type(4)));
#define MFMA16(a, b, c) __builtin_amdgcn_mfma_f32_16x16x32_bf16(a, b, c, 0, 0, 0)

__device__ __forceinline__ float bf2f(uint_t u) { return __uint_as_float(u << 16); }
__device__ __forceinline__ ushort_t f2bf(float f) {
  uint_t x = __float_as_uint(f);
  return (ushort_t)((x + 0x7fffu + ((x >> 16) & 1u)) >> 16);  // RNE
}
__device__ __forceinline__ uint_t cvtpk(float lo, float hi) {
  uint_t r;
  asm("v_cvt_pk_bf16_f32 %0, %1, %2" : "=v"(r) : "v"(lo), "v"(hi));
  return r;
}
// async global->LDS, 16B per lane; LDS dest is wave-uniform base + lane*16
__device__ __forceinline__ void gload_lds16(const void* g, void* l) {
  __builtin_amdgcn_global_load_lds(
      (const __attribute__((address_space(1))) unsigned int*)g,
      (__attribute__((address_space(3))) unsigned int*)l, 16, 0, 0);
}

// B=64,R=32 -> N=2048; L=64; C0=128, C1=C2=256, C3=16. f32 inputs/output.
#define NBATCH 2048

// ---------- pre0: per-n channel means of H + V2_0[n][o]; blocks<128 also cvt W0 ----------
__global__ __launch_bounds__(256) void pre0_kernel(
    const float* __restrict__ Hr, const float* __restrict__ Hi,
    const float* __restrict__ P2_0, const float* __restrict__ P1_0,
    ushort_t* __restrict__ W0bf, float* __restrict__ V20)
{
  __shared__ float r[4][128];
  __shared__ float hm[128];
  const int t = threadIdx.x, n = blockIdx.x;
  if (n < 128) {
    int i = n * 256 + t;
    W0bf[i] = f2bf(P1_0[i]);
  }
  const int q = t >> 6;
  const int c = (2 * t) & 127;
  const int cc = c & 63;
  const float* src = ((c < 64) ? Hr : Hi) + (size_t)n * 4096 + cc;
  float s0 = 0.f, s1 = 0.f;
  #pragma unroll
  for (int i = 0; i < 16; i++) {
    int l = 4 * i + q;
    float2 x = *(const float2*)(src + l * 64);
    s0 += x.x; s1 += x.y;
  }
  r[q][c] = s0; r[q][c + 1] = s1;
  __syncthreads();
  if (t < 128) hm[t] = (r[0][t] + r[1][t] + r[2][t] + r[3][t]) * (1.0f / 64.0f);
  __syncthreads();
  const float4* pw = (const float4*)(P2_0 + t * 128);
  float s = 0.f;
  #pragma unroll 8
  for (int c4 = 0; c4 < 32; c4++) {
    float4 p = pw[c4];
    s = fmaf(p.x, hm[4 * c4 + 0], s);
    s = fmaf(p.y, hm[4 * c4 + 1], s);
    s = fmaf(p.z, hm[4 * c4 + 2], s);
    s = fmaf(p.w, hm[4 * c4 + 3], s);
  }
  V20[n * 256 + t] = 0.1f * s;
}

// ---------- layer0: dbuf 2-batch async-staged (f32, swizzled) MFMA GEMM(128->256) ----------
__global__ __launch_bounds__(256) void layer0_mfma_kernel(
    const float* __restrict__ Hr, const float* __restrict__ Hi,
    const ushort_t* __restrict__ W0bf, const float* __restrict__ V20,
    ushort_t* __restrict__ Z, float* __restrict__ partA, float* __restrict__ partB)
{
  __shared__ __align__(16) ushort_t lds[2][64 * 264];  // 2 x 33.8 KB regions
  const int t = threadIdx.x, nb = blockIdx.x;
  const int lane = t & 63, w = t >> 6, r16 = lane & 15, g4 = lane >> 4;
  const int sw = r16 & 7;

  auto stageH = [&](float* bufF, int n) {
    #pragma unroll
    for (int i = 0; i < 8; i++) {
      int G = (w * 8 + i) * 64 + lane;
      int row = G >> 5;
      int gc = G & 31;
      int gsrc = gc ^ (row & 7);
      int fi = gsrc * 4;   // f32 col in [0,128): <64 Hr else Hi
      const float* src = ((fi < 64) ? Hr : Hi) + (size_t)n * 4096 + row * 64 + (fi & 63);
      gload_lds16(src, bufF + (w * 8 + i) * 256);
    }
  };

  stageH((float*)&lds[0][0], 2 * nb);
  __syncthreads();                         // buf0 staged
  stageH((float*)&lds[1][0], 2 * nb + 1);  // async; overlaps half-0 compute

  #pragma unroll
  for (int half = 0; half < 2; half++) {
    const int n = 2 * nb + half;
    ushort_t* buf = &lds[half][0];
    float* bufF = (float*)buf;

    float4 v2r[4];
    #pragma unroll
    for (int m = 0; m < 4; m++)
      v2r[m] = *(const float4*)(V20 + n * 256 + w * 64 + m * 16 + g4 * 4);

    f32x4 acc[4][4];
    #pragma unroll
    for (int i = 0; i < 4; i++)
      #pragma unroll
      for (int j = 0; j < 4; j++) acc[i][j] = (f32x4){0.f, 0.f, 0.f, 0.f};

    #pragma unroll
    for (int kk = 0; kk < 4; kk++) {
      bf16x8 aF[4], bF[4];
      #pragma unroll
      for (int m = 0; m < 4; m++)
        aF[m] = *(const bf16x8*)(W0bf + (w * 64 + m * 16 + r16) * 128 + kk * 32 + g4 * 8);
      #pragma unroll
      for (int nt = 0; nt < 4; nt++) {
        const int row = nt * 16 + r16;
        const float* base = bufF + row * 128;
        const int g0 = kk * 8 + g4 * 2;
        float4 xa = *(const float4*)(base + ((g0 ^ sw) * 4));
        float4 xb = *(const float4*)(base + (((g0 + 1) ^ sw) * 4));
        uint4 u = make_uint4(cvtpk(xa.x, xa.y), cvtpk(xa.z, xa.w),
                             cvtpk(xb.x, xb.y), cvtpk(xb.z, xb.w));
        bF[nt] = *(const bf16x8*)&u;
      }
      #pragma unroll
      for (int m = 0; m < 4; m++)
        #pragma unroll
        for (int nt = 0; nt < 4; nt++)
          acc[m][nt] = MFMA16(aF[m], bF[nt], acc[m][nt]);
    }

    // fused stats
    #pragma unroll
    for (int m = 0; m < 4; m++) {
      float s[4] = {0.f, 0.f, 0.f, 0.f}, q[4] = {0.f, 0.f, 0.f, 0.f};
      #pragma unroll
      for (int nt = 0; nt < 4; nt++)
        #pragma unroll
        for (int r = 0; r < 4; r++) {
          float v = fmaxf(acc[m][nt][r] + v2r[m][r], 0.f);
          s[r] += v; q[r] = fmaf(v, v, q[r]);
        }
      #pragma unroll
      for (int b = 1; b < 16; b <<= 1)
        #pragma unroll
        for (int r = 0; r < 4; r++) {
          s[r] += __shfl_xor(s[r], b);
          q[r] += __shfl_xor(q[r], b);
        }
      const int ob = w * 64 + m * 16 + g4 * 4;
      #pragma unroll
      for (int r = 0; r < 4; r++)
        if (r16 == r) {
          partA[n * 256 + ob + r] = s[r];
          partB[n * 256 + ob + r] = q[r];
        }
    }

    __syncthreads();   // buf reads done (half 0: also drains buf1 stage)
    #pragma unroll
    for (int m = 0; m < 4; m++) {
      const int ob = w * 64 + m * 16 + g4 * 4;
      #pragma unroll
      for (int nt = 0; nt < 4; nt++) {
        const int l = nt * 16 + r16;
        uint_t p0 = cvtpk(fmaxf(acc[m][nt][0] + v2r[m].x, 0.f),
                          fmaxf(acc[m][nt][1] + v2r[m].y, 0.f));
        uint_t p1 = cvtpk(fmaxf(acc[m][nt][2] + v2r[m].z, 0.f),
                          fmaxf(acc[m][nt][3] + v2r[m].w, 0.f));
        *(uint2*)(&buf[l * 264 + ob]) = make_uint2(p0, p1);
      }
    }
    __syncthreads();
    #pragma unroll
    for (int i = 0; i < 8; i++) {
      int el = i * 2048 + t * 8;
      int l = el >> 8, o0 = el & 255;
      *(uint4*)(&Z[(size_t)n * 16384 + el]) = *(const uint4*)(&buf[l * 264 + o0]);
    }
  }
}

// ---------- statsfin ----------
__global__ __launch_bounds__(256) void statsfin_kernel(
    const float* __restrict__ partA, const float* __restrict__ partB,
    const float* __restrict__ bnw, const float* __restrict__ bnb,
    float* __restrict__ stats)
{
  __shared__ float s1s[256], s2s[256];
  const int c = blockIdx.x, t = threadIdx.x;
  float s1 = 0.f, s2 = 0.f;
  #pragma unroll
  for (int j = 0; j < 8; j++) {
    int n = t * 8 + j;
    s1 += partA[n * 256 + c];
    s2 += partB[n * 256 + c];
  }
  s1s[t] = s1; s2s[t] = s2;
  __syncthreads();
  for (int s = 128; s > 0; s >>= 1) {
    if (t < s) { s1s[t] += s1s[t + s]; s2s[t] += s2s[t + s]; }
    __syncthreads();
  }
  if (t == 0) {
    const float inv = 1.0f / 131072.0f;
    float mu = s1s[0] * inv;
    float var = fmaxf(s2s[0] * inv - mu * mu, 0.f);
    float rstd = rsqrtf(var + 1e-5f);
    float sc = rstd * bnw[c];
    stats[2 * c]     = sc;
    stats[2 * c + 1] = bnb[c] - mu * sc;
  }
}

// ---------- prep ----------
__global__ __launch_bounds__(256) void prep_kernel(
    const float* __restrict__ P1f, const float* __restrict__ P2f,
    const float* __restrict__ stats, ushort_t* __restrict__ Wbf,
    float* __restrict__ P2s, float* __restrict__ biasT)
{
  const int o = blockIdx.x, t = threadIdx.x;
  float sc = stats[2 * t], sh = stats[2 * t + 1];
  float w = P1f[o * 256 + t];
  Wbf[o * 256 + t] = f2bf(w * sc);
  float p = P2f[o * 256 + t];
  P2s[o * 256 + t] = p * sc;
  __shared__ float s1[256], s2[256];
  s1[t] = w * sh;
  s2[t] = p * sh;
  __syncthreads();
  for (int s = 128; s > 0; s >>= 1) {
    if (t < s) { s1[t] += s1[t + s]; s2[t] += s2[t + s]; }
    __syncthreads();
  }
  if (t == 0) biasT[o] = s1[0] + 0.1f * s2[0];
}

// ---------- v2n: V2[n][o] = 0.1 * P2s[o,:].(partA[n]/64) + biasT[o]; 4 n/block ----------
__global__ __launch_bounds__(256) void v2n_kernel(
    const float* __restrict__ partA, const float* __restrict__ P2s,
    const float* __restrict__ biasT, float* __restrict__ V2)
{
  __shared__ float zm[4][256];
  const int t = threadIdx.x, n0 = blockIdx.x * 4;
  #pragma unroll
  for (int j = 0; j < 4; j++) zm[j][t] = partA[(n0 + j) * 256 + t] * (1.0f / 64.0f);
  __syncthreads();
  float s[4] = {0.f, 0.f, 0.f, 0.f};
  const float4* pw = (const float4*)(P2s + t * 256);
  #pragma unroll 4
  for (int c4 = 0; c4 < 64; c4++) {
    float4 p = pw[c4];
    #pragma unroll
    for (int j = 0; j < 4; j++) {
      s[j] = fmaf(p.x, zm[j][4 * c4 + 0], s[j]);
      s[j] = fmaf(p.y, zm[j][4 * c4 + 1], s[j]);
      s[j] = fmaf(p.z, zm[j][4 * c4 + 2], s[j]);
      s[j] = fmaf(p.w, zm[j][4 * c4 + 3], s[j]);
    }
  }
  float b = biasT[t];
  #pragma unroll
  for (int j = 0; j < 4; j++) V2[(n0 + j) * 256 + t] = 0.1f * s[j] + b;
}

// ---------- layer1: single-buffer async-staged (bf16, swizzled) MFMA GEMM(256->256); in-place Z ----------
__global__ __launch_bounds__(256) void layer1_mfma_kernel(
    ushort_t* Z, const ushort_t* __restrict__ W1bf, const float* __restrict__ V21,
    float* __restrict__ partA, float* __restrict__ partB)
{
  __shared__ __align__(16) ushort_t lds[64 * 264];   // staged Z 32KB; reused as trans
  const int t = threadIdx.x, n = blockIdx.x;
  const int lane = t & 63, w = t >> 6, r16 = lane & 15, g4 = lane >> 4;
  const size_t zbase = (size_t)n * 16384;

  #pragma unroll
  for (int i = 0; i < 8; i++) {
    int G = (w * 8 + i) * 64 + lane;
    int row = G >> 5;
    int gc = G & 31;
    int gsrc = gc ^ (row & 7);
    gload_lds16(Z + zbase + row * 256 + gsrc * 8, &lds[(w * 8 + i) * 512]);
  }

  float4 v2r[4];
  #pragma unroll
  for (int m = 0; m < 4; m++)
    v2r[m] = *(const float4*)(V21 + n * 256 + w * 64 + m * 16 + g4 * 4);

  f32x4 acc[4][4];
  #pragma unroll
  for (int i = 0; i < 4; i++)
    #pragma unroll
    for (int j = 0; j < 4; j++) acc[i][j] = (f32x4){0.f, 0.f, 0.f, 0.f};

  bf16x8 aF[2][4];
  #pragma unroll
  for (int m = 0; m < 4; m++)
    aF[0][m] = *(const bf16x8*)(W1bf + (w * 64 + m * 16 + r16) * 256 + g4 * 8);

  __syncthreads();   // barrier drains vmcnt -> staging complete

  const int sw = r16 & 7;
  #pragma unroll
  for (int kk = 0; kk < 8; kk++) {
    const int cur = kk & 1, nxt = cur ^ 1;
    if (kk < 7) {
      #pragma unroll
      for (int m = 0; m < 4; m++)
        aF[nxt][m] = *(const bf16x8*)(W1bf + (w * 64 + m * 16 + r16) * 256 + (kk + 1) * 32 + g4 * 8);
    }
    bf16x8 bF[4];
    #pragma unroll
    for (int nt = 0; nt < 4; nt++) {
      const int row = nt * 16 + r16;
      bF[nt] = *(const bf16x8*)(&lds[row * 256 + (((kk * 4 + g4) ^ sw) * 8)]);
    }
    #pragma unroll
    for (int m = 0; m < 4; m++)
      #pragma unroll
      for (int nt = 0; nt < 4; nt++)
        acc[m][nt] = MFMA16(aF[cur][m], bF[nt], acc[m][nt]);
  }

  #pragma unroll
  for (int m = 0; m < 4; m++) {
    float s[4] = {0.f, 0.f, 0.f, 0.f}, q[4] = {0.f, 0.f, 0.f, 0.f};
    #pragma unroll
    for (int nt = 0; nt < 4; nt++)
      #pragma unroll
      for (int r = 0; r < 4; r++) {
        float v = fmaxf(acc[m][nt][r] + v2r[m][r], 0.f);
        s[r] += v; q[r] = fmaf(v, v, q[r]);
      }
    #pragma unroll
    for (int b = 1; b < 16; b <<= 1)
      #pragma unroll
      for (int r = 0; r < 4; r++) {
        s[r] += __shfl_xor(s[r], b);
        q[r] += __shfl_xor(q[r], b);
      }
    const int ob = w * 64 + m * 16 + g4 * 4;
    #pragma unroll
    for (int r = 0; r < 4; r++)
      if (r16 == r) {
        partA[n * 256 + ob + r] = s[r];
        partB[n * 256 + ob + r] = q[r];
      }
  }

  __syncthreads();   // lds reads done; reuse as trans
  #pragma unroll
  for (int m = 0; m < 4; m++) {
    const int ob = w * 64 + m * 16 + g4 * 4;
    #pragma unroll
    for (int nt = 0; nt < 4; nt++) {
      const int l = nt * 16 + r16;
      uint_t p0 = cvtpk(fmaxf(acc[m][nt][0] + v2r[m].x, 0.f),
                        fmaxf(acc[m][nt][1] + v2r[m].y, 0.f));
      uint_t p1 = cvtpk(fmaxf(acc[m][nt][2] + v2r[m].z, 0.f),
                        fmaxf(acc[m][nt][3] + v2r[m].w, 0.f));
      *(uint2*)(&lds[l * 264 + ob]) = make_uint2(p0, p1);
    }
  }
  __syncthreads();
  #pragma unroll
  for (int i = 0; i < 8; i++) {
    int el = i * 2048 + t * 8;
    int l = el >> 8, o0 = el & 255;
    *(uint4*)(&Z[zbase + el]) = *(const uint4*)(&lds[l * 264 + o0]);
  }
}

// ---------- layer2 + final + v2w fused ----------
__global__ __launch_bounds__(256) void layer2final_kernel(
    const ushort_t* __restrict__ Z, const ushort_t* __restrict__ W2bf,
    const float* __restrict__ partA, const float* __restrict__ P2s2,
    const float* __restrict__ biasT2, const float* __restrict__ Vh,
    float* __restrict__ out)
{
  __shared__ float zm[256];
  __shared__ float red[16][17];
  __shared__ float v2s[16];
  __shared__ float zf[16][65];
  __shared__ float invn[16];
  const int t = threadIdx.x, n = blockIdx.x;
  const int lane = t & 63, w = t >> 6, r16 = lane & 15, g4 = lane >> 4;
  const size_t zbase = (size_t)n * 16384;

  zm[t] = partA[n * 256 + t] * (1.0f / 64.0f);

  f32x4 acc = (f32x4){0.f, 0.f, 0.f, 0.f};
  #pragma unroll 2
  for (int kk = 0; kk < 8; kk++) {
    bf16x8 aF = *(const bf16x8*)(W2bf + r16 * 256 + kk * 32 + g4 * 8);
    bf16x8 bF = *(const bf16x8*)(Z + zbase + (w * 16 + r16) * 256 + kk * 32 + g4 * 8);
    acc = MFMA16(aF, bF, acc);
  }
  __syncthreads();   // zm visible
  {
    const int oi = t & 15, ch = t >> 4;
    const float4* pw = (const float4*)(P2s2 + oi * 256 + ch * 16);
    float s = 0.f;
    #pragma unroll
    for (int c4 = 0; c4 < 4; c4++) {
      float4 p = pw[c4];
      int cb = ch * 16 + c4 * 4;
      s = fmaf(p.x, zm[cb + 0], s);
      s = fmaf(p.y, zm[cb + 1], s);
      s = fmaf(p.z, zm[cb + 2], s);
      s = fmaf(p.w, zm[cb + 3], s);
    }
    red[ch][oi] = s;
  }
  __syncthreads();
  if (t < 16) {
    float a = 0.f;
    #pragma unroll
    for (int c = 0; c < 16; c++) a += red[c][t];
    v2s[t] = 0.1f * a + biasT2[t];
  }
  __syncthreads();
  #pragma unroll
  for (int r = 0; r < 4; r++) {
    int o = g4 * 4 + r;
    zf[o][w * 16 + r16] = acc[r] + v2s[o];
  }
  __syncthreads();
  if (t < 16) {
    float s = 0.f;
    #pragma unroll
    for (int l = 0; l < 64; l++) s = fmaf(zf[t][l], zf[t][l], s);
    invn[t] = (s > 0.f) ? (8.0f * rsqrtf(s)) : 0.f;
  }
  __syncthreads();
  const size_t base = (size_t)n * 4096;
  #pragma unroll
  for (int g = 0; g < 4; g++) {
    int e = t * 16 + g * 4;
    int l = e >> 6;
    int k = (e >> 2) & 15;
    float val = zf[k][l] * invn[k];
    float4 vv = *(const float4*)(Vh + base + e);
    *(float4*)(out + base + e) =
        make_float4(vv.x * val, vv.y * val, vv.z * val, vv.w * val);
  }
}

extern "C" void kernel_launch(void* const* d_in, const int* in_sizes, int n_in,
                              void* d_out, int out_size, void* d_ws, size_t ws_size,
                              hipStream_t stream) {
  const float* Hr   = (const float*)d_in[0];
  const float* Hi   = (const float*)d_in[1];
  const float* Vh   = (const float*)d_in[2];
  const float* P1_0 = (const float*)d_in[3];
  const float* P2_0 = (const float*)d_in[4];
  const float* bnw0 = (const float*)d_in[5];
  const float* bnb0 = (const float*)d_in[6];
  const float* P1_1 = (const float*)d_in[7];
  const float* P2_1 = (const float*)d_in[8];
  const float* bnw1 = (const float*)d_in[9];
  const float* bnb1 = (const float*)d_in[10];
  const float* P1_2 = (const float*)d_in[11];
  const float* P2_2 = (const float*)d_in[12];

  char* ws = (char*)d_ws;
  float*    stats0 = (float*)   (ws);             // 2048
  float*    stats1 = (float*)   (ws + 2048);      // 2048
  float*    biasT  = (float*)   (ws + 4096);      // 1024
  float*    biasT2 = (float*)   (ws + 5120);      // 1024
  ushort_t* W0bf   = (ushort_t*)(ws + 8192);      // 65536
  ushort_t* W1bf   = (ushort_t*)(ws + 73728);     // 131072
  ushort_t* W2bf   = (ushort_t*)(ws + 204800);    // 8192
  float*    P2s1   = (float*)   (ws + 212992);    // 262144
  float*    P2s2   = (float*)   (ws + 475136);    // 16384
  float*    partA  = (float*)   (ws + 491520);    // 2097152
  float*    partB  = (float*)   (ws + 2588672);   // 2097152
  float*    V20    = (float*)   (ws + 4685824);   // 2097152
  float*    V21    = (float*)   (ws + 6782976);   // 2097152
  ushort_t* Z      = (ushort_t*)(ws + 9437184);   // 67108864 -> end 76,546,048

  pre0_kernel<<<NBATCH, 256, 0, stream>>>(Hr, Hi, P2_0, P1_0, W0bf, V20);
  layer0_mfma_kernel<<<NBATCH / 2, 256, 0, stream>>>(Hr, Hi, W0bf, V20, Z, partA, partB);
  statsfin_kernel<<<256, 256, 0, stream>>>(partA, partB, bnw0, bnb0, stats0);
  prep_kernel<<<256, 256, 0, stream>>>(P1_1, P2_1, stats0, W1bf, P2s1, biasT);
  v2n_kernel<<<512, 256, 0, stream>>>(partA, P2s1, biasT, V21);
  layer1_mfma_kernel<<<NBATCH, 256, 0, stream>>>(Z, W1bf, V21, partA, partB);
  statsfin_kernel<<<256, 256, 0, stream>>>(partA, partB, bnw1, bnb1, stats1);
  prep_kernel<<<16, 256, 0, stream>>>(P1_2, P2_2, stats1, W2bf, P2s2, biasT2);
  layer2final_kernel<<<NBATCH, 256, 0, stream>>>(Z, W2bf, partA, P2s2, biasT2, Vh, (float*)d_out);
}